// Round 1
// baseline (1794.560 us; speedup 1.0000x reference)
//
#include <hip/hip_runtime.h>

#define TOKENS 8192
#define IN_F   4096
#define OUT_F  11008

typedef __attribute__((ext_vector_type(8))) short bf16x8;
typedef __attribute__((ext_vector_type(4))) float floatx4;

__device__ __forceinline__ unsigned short f32_to_bf16(float f) {
  union { float f; unsigned int u; } v; v.f = f;
  unsigned int r = v.u + 0x7FFFu + ((v.u >> 16) & 1u);   // round-to-nearest-even
  return (unsigned short)(r >> 16);
}

__device__ __forceinline__ void gload_lds16(const void* g, void* l) {
  __builtin_amdgcn_global_load_lds(
      (const __attribute__((address_space(1))) void*)g,
      (__attribute__((address_space(3))) void*)l,
      16, 0, 0);
}

// ---- x: fp32 -> bf16 (8 elems/thread, 16B stores) ----
__global__ __launch_bounds__(256) void convert_x_kernel(
    const float* __restrict__ x, unsigned short* __restrict__ xb) {
  int idx = (blockIdx.x * 256 + threadIdx.x) * 8;
  const float4* p = (const float4*)(x + idx);
  float4 f0 = p[0], f1 = p[1];
  bf16x8 o;
  o[0] = (short)f32_to_bf16(f0.x); o[1] = (short)f32_to_bf16(f0.y);
  o[2] = (short)f32_to_bf16(f0.z); o[3] = (short)f32_to_bf16(f0.w);
  o[4] = (short)f32_to_bf16(f1.x); o[5] = (short)f32_to_bf16(f1.y);
  o[6] = (short)f32_to_bf16(f1.z); o[7] = (short)f32_to_bf16(f1.w);
  *(bf16x8*)(xb + idx) = o;
}

// ---- W: int32 (values in [-128,127]) -> bf16, exact ----
__global__ __launch_bounds__(256) void convert_w_kernel(
    const int* __restrict__ w, unsigned short* __restrict__ wb) {
  int idx = (blockIdx.x * 256 + threadIdx.x) * 8;
  const int4* p = (const int4*)(w + idx);
  int4 a = p[0], b = p[1];
  bf16x8 o;
  o[0] = (short)f32_to_bf16((float)a.x); o[1] = (short)f32_to_bf16((float)a.y);
  o[2] = (short)f32_to_bf16((float)a.z); o[3] = (short)f32_to_bf16((float)a.w);
  o[4] = (short)f32_to_bf16((float)b.x); o[5] = (short)f32_to_bf16((float)b.y);
  o[6] = (short)f32_to_bf16((float)b.z); o[7] = (short)f32_to_bf16((float)b.w);
  *(bf16x8*)(wb + idx) = o;
}

// ---- m97-structure bf16 GEMM: C = A * B^T, fused scale+bias ----
// A [TOKENS][IN_F] bf16, B [OUT_F][IN_F] bf16. 128x128 tile, BK=32,
// 256 threads = 4 waves in 2x2, each wave 64x64 via 4x4 of 16x16x32 MFMA.
__global__ __launch_bounds__(256, 2) void qlinear_gemm(
    const unsigned short* __restrict__ A,
    const unsigned short* __restrict__ B,
    const float* __restrict__ scales,
    const float* __restrict__ bias,
    float* __restrict__ out) {
  __shared__ __align__(16) unsigned short As[128 * 32];
  __shared__ __align__(16) unsigned short Bs[128 * 32];

  const int t    = threadIdx.x;
  const int lane = t & 63;
  const int w    = t >> 6;
  const int m0   = blockIdx.y * 128;
  const int n0   = blockIdx.x * 128;

  // global->LDS staging: thread t stages flat elems [t*8, t*8+8) of each
  // 128x32 tile half (instr i covers rows i*64..i*64+63). LDS dst is
  // wave-uniform (HW scatters lane*16B).
  const int srow = t >> 2;            // 0..63
  const int scol = (t & 3) * 8;       // 0,8,16,24
  const unsigned short* gA = A + (size_t)(m0 + srow) * IN_F + scol;
  const unsigned short* gB = B + (size_t)(n0 + srow) * IN_F + scol;
  unsigned short* ldsA = As + w * 512;
  unsigned short* ldsB = Bs + w * 512;

  // fragment bases: A-operand layout m=lane&15, k=(lane>>4)*8+j
  const int fr = lane & 15;
  const int fk = (lane >> 4) * 8;
  const int wm = (w >> 1) * 64;
  const int wn = (w & 1) * 64;
  const bf16x8* pa = (const bf16x8*)(As + (wm + fr) * 32 + fk);
  const bf16x8* pb = (const bf16x8*)(Bs + (wn + fr) * 32 + fk);

  floatx4 acc[4][4];
#pragma unroll
  for (int mi = 0; mi < 4; ++mi)
#pragma unroll
    for (int ni = 0; ni < 4; ++ni)
      acc[mi][ni] = (floatx4){0.f, 0.f, 0.f, 0.f};

  for (int kt = 0; kt < IN_F / 32; ++kt) {
    __syncthreads();                       // previous tile consumed
    gload_lds16(gA,              ldsA);
    gload_lds16(gA + 64 * IN_F,  ldsA + 2048);
    gload_lds16(gB,              ldsB);
    gload_lds16(gB + 64 * IN_F,  ldsB + 2048);
    gA += 32; gB += 32;
    __syncthreads();                       // vmcnt(0) drain -> tile visible

    bf16x8 af[4], bf[4];
#pragma unroll
    for (int i = 0; i < 4; ++i) {
      af[i] = pa[i * 64];                  // +16 rows per step (16*32/8=64)
      bf[i] = pb[i * 64];
    }
#pragma unroll
    for (int mi = 0; mi < 4; ++mi)
#pragma unroll
      for (int ni = 0; ni < 4; ++ni)
        acc[mi][ni] = __builtin_amdgcn_mfma_f32_16x16x32_bf16(
            af[mi], bf[ni], acc[mi][ni], 0, 0, 0);
  }

  // epilogue: D row = (lane>>4)*4 + r (M), col = lane&15 (N)
  const int rq = (lane >> 4) << 2;
#pragma unroll
  for (int ni = 0; ni < 4; ++ni) {
    const int col = n0 + wn + ni * 16 + (lane & 15);
    const float s = scales[col];
    const float bb = bias[col];
#pragma unroll
    for (int mi = 0; mi < 4; ++mi) {
      const int rowb = m0 + wm + mi * 16 + rq;
#pragma unroll
      for (int r = 0; r < 4; ++r) {
        out[(size_t)(rowb + r) * OUT_F + col] = acc[mi][ni][r] * s + bb;
      }
    }
  }
}

extern "C" void kernel_launch(void* const* d_in, const int* in_sizes, int n_in,
                              void* d_out, int out_size, void* d_ws, size_t ws_size,
                              hipStream_t stream) {
  const float* x      = (const float*)d_in[0];
  const int*   wq     = (const int*)d_in[1];    // int8 values stored as int32 per harness contract
  const float* scales = (const float*)d_in[2];
  const float* bias   = (const float*)d_in[3];
  float* out = (float*)d_out;

  unsigned short* Xb = (unsigned short*)d_ws;                                   // 67 MB
  unsigned short* Wb = (unsigned short*)((char*)d_ws + (size_t)TOKENS * IN_F * 2); // +90 MB

  convert_x_kernel<<<TOKENS * IN_F / (256 * 8), 256, 0, stream>>>(x, Xb);
  convert_w_kernel<<<OUT_F * IN_F / (256 * 8), 256, 0, stream>>>(wq, Wb);
  qlinear_gemm<<<dim3(OUT_F / 128, TOKENS / 128), 256, 0, stream>>>(
      Xb, Wb, scales, bias, out);
}